// Round 4
// baseline (381.892 us; speedup 1.0000x reference)
//
#include <hip/hip_runtime.h>
#include <math.h>

// Grid constants from the reference
#define GH 512
#define GW 512
#define GHW (GH * GW)
#define RR 3

// Precision model (round 4): pure f32 chain, but voxel coordinate uses
// multiply-by-reciprocal (px = (x - XMIN) * 10.0f) instead of division by
// 0.1f. 1/0.1 == 10.0 exactly in f64, and XLA / precomputed-scale numpy
// references canonically use the reciprocal form; x*10.0f differs from
// x/0.1f by ~1 ulp one-sided, which explains the stable flip population
// seen in rounds 1-3.

__device__ __forceinline__ void inv4x4_f64(const float* A, double Minv[16]) {
    double M[4][8];
    for (int i = 0; i < 4; i++) {
        for (int j = 0; j < 4; j++) {
            M[i][j] = (double)A[i * 4 + j];
            M[i][j + 4] = (i == j) ? 1.0 : 0.0;
        }
    }
    for (int c = 0; c < 4; c++) {
        int p = c;
        double best = fabs(M[c][c]);
        for (int r = c + 1; r < 4; r++) {
            double v = fabs(M[r][c]);
            if (v > best) { best = v; p = r; }
        }
        if (p != c) {
            for (int j = 0; j < 8; j++) {
                double t = M[c][j]; M[c][j] = M[p][j]; M[p][j] = t;
            }
        }
        double ip = 1.0 / M[c][c];
        for (int j = 0; j < 8; j++) M[c][j] *= ip;
        for (int r = 0; r < 4; r++) {
            if (r == c) continue;
            double f = M[r][c];
            if (f != 0.0) {
                for (int j = 0; j < 8; j++) M[r][j] -= f * M[c][j];
            }
        }
    }
    for (int i = 0; i < 4; i++)
        for (int j = 0; j < 4; j++)
            Minv[i * 4 + j] = M[i][j + 4];
}

// pose_0to1 = inv(pose1) @ pose0, stored f32. For these translation-only
// poses the f64 compute + f32 cast is bitwise equal to the pure-f32 chain
// (single correctly-rounded subtraction t0 - t1).
__global__ void pose_kernel(const float* __restrict__ pose0,
                            const float* __restrict__ pose1,
                            float* __restrict__ pose_out, int B) {
    int b = blockIdx.x * blockDim.x + threadIdx.x;
    if (b >= B) return;
    double inv1[16];
    inv4x4_f64(pose1 + b * 16, inv1);
    const float* P0 = pose0 + b * 16;
    float* O = pose_out + b * 16;
    for (int i = 0; i < 4; i++) {
        for (int j = 0; j < 4; j++) {
            double s = 0.0;
            for (int k = 0; k < 4; k++) s += inv1[i * 4 + k] * (double)P0[k * 4 + j];
            O[i * 4 + j] = (float)s;
        }
    }
}

// f32 transform (exact for identity rotation), f32 voxelize with *10.0f scale.
__device__ __forceinline__ void voxelize_f32(const float* __restrict__ p,
                                             const float* __restrict__ T, // or nullptr
                                             float& px, float& py,
                                             int& ix, int& iy, bool& valid) {
    float x = p[0], y = p[1], z = p[2];
    if (T) {
        float nx = T[0] * x + T[1] * y + T[2] * z + T[3];
        float ny = T[4] * x + T[5] * y + T[6] * z + T[7];
        float nz = T[8] * x + T[9] * y + T[10] * z + T[11];
        x = nx; y = ny; z = nz;
    }
    px = (x - 0.0f) * 10.0f;
    py = (y - (-25.6f)) * 10.0f;
    ix = (int)floorf(px);
    iy = (int)floorf(py);
    valid = (ix >= 0) & (ix < GH) & (iy >= 0) & (iy < GW) &
            (z >= -3.0f) & (z < 3.0f);
}

// Splat 7x7 gaussian footprint per valid radar point; float-max via int atomicMax
// (all values positive, heat zero-initialized -> int bit patterns order correctly).
__global__ void splat_kernel(const float* __restrict__ radar, // (B, M, 6)
                             const float* __restrict__ pose,  // (B, 16)
                             float* __restrict__ heat,        // (B, GH, GW)
                             int B, int M, int use_pose) {
    int tid = blockIdx.x * blockDim.x + threadIdx.x;
    if (tid >= B * M) return;
    int b = tid / M;
    const float* p = radar + (size_t)tid * 6;
    float px, py; int ix, iy; bool valid;
    voxelize_f32(p, use_pose ? (pose + b * 16) : nullptr, px, py, ix, iy, valid);
    if (!valid) return;
    int* hb = (int*)(heat + (size_t)b * GHW);
    for (int dx = -RR; dx <= RR; dx++) {
        int gx = ix + dx;
        if (gx < 0 || gx >= GH) continue;
        float ddx = ((float)gx + 0.5f) - px;
        for (int dy = -RR; dy <= RR; dy++) {
            int gy = iy + dy;
            if (gy < 0 || gy >= GW) continue;
            float ddy = ((float)gy + 0.5f) - py;
            float d2 = ddx * ddx + ddy * ddy;
            float val = expf(-d2 / 4.5f);
            atomicMax(hb + gx * GW + gy, __float_as_int(val));
        }
    }
}

// Gather one output segment: per point -> (optional transform) -> voxel -> heat sample
__global__ void gather_kernel(const float* __restrict__ pts,  // (B, per_b, stride)
                              const float* __restrict__ pose,
                              const float* __restrict__ heat, // (B, GH, GW)
                              float* __restrict__ out,        // (B, row_len)
                              int B, int per_b, int stride, int use_pose,
                              int row_len, int seg_off) {
    int tid = blockIdx.x * blockDim.x + threadIdx.x;
    if (tid >= B * per_b) return;
    int b = tid / per_b;
    int n = tid - b * per_b;
    const float* p = pts + (size_t)tid * stride;
    float px, py; int ix, iy; bool valid;
    voxelize_f32(p, use_pose ? (pose + b * 16) : nullptr, px, py, ix, iy, valid);
    float v = 0.0f;
    if (valid) v = heat[(size_t)b * GHW + ix * GW + iy];
    out[(size_t)b * row_len + seg_off + n] = v;
}

extern "C" void kernel_launch(void* const* d_in, const int* in_sizes, int n_in,
                              void* d_out, int out_size, void* d_ws, size_t ws_size,
                              hipStream_t stream) {
    const float* pc0      = (const float*)d_in[0];
    const float* pc1      = (const float*)d_in[1];
    const float* radar0   = (const float*)d_in[2];
    const float* radar1   = (const float*)d_in[3];
    const float* pose0    = (const float*)d_in[4];
    const float* pose1    = (const float*)d_in[5];
    float* out = (float*)d_out;

    int B = in_sizes[4] / 16;
    int N = in_sizes[0] / (B * 3);
    int M = in_sizes[2] / (B * 6);
    int row_len = 2 * N + 2 * M;

    // workspace layout: heat0 (B*GHW f32) | heat1 (B*GHW f32) | pose (B*16 f32)
    float* heat0 = (float*)d_ws;
    float* heat1 = heat0 + (size_t)B * GHW;
    float* pose_ws = heat1 + (size_t)B * GHW;

    // zero both heatmaps (workspace is re-poisoned before every call)
    hipMemsetAsync(d_ws, 0, (size_t)2 * B * GHW * sizeof(float), stream);

    pose_kernel<<<1, 64, 0, stream>>>(pose0, pose1, pose_ws, B);

    int splat_threads = B * M;
    splat_kernel<<<(splat_threads + 255) / 256, 256, 0, stream>>>(
        radar0, pose_ws, heat0, B, M, 1);
    splat_kernel<<<(splat_threads + 255) / 256, 256, 0, stream>>>(
        radar1, pose_ws, heat1, B, M, 0);

    // gather segments: [lidar0 | radar0 | lidar1 | radar1] per batch row
    int gl = B * N, gr = B * M;
    gather_kernel<<<(gl + 255) / 256, 256, 0, stream>>>(
        pc0, pose_ws, heat0, out, B, N, 3, 1, row_len, 0);
    gather_kernel<<<(gr + 255) / 256, 256, 0, stream>>>(
        radar0, pose_ws, heat0, out, B, M, 6, 1, row_len, N);
    gather_kernel<<<(gl + 255) / 256, 256, 0, stream>>>(
        pc1, pose_ws, heat1, out, B, N, 3, 0, row_len, N + M);
    gather_kernel<<<(gr + 255) / 256, 256, 0, stream>>>(
        radar1, pose_ws, heat1, out, B, M, 6, 0, row_len, 2 * N + M);
}